// Round 1
// baseline (2732.521 us; speedup 1.0000x reference)
//
#include <hip/hip_runtime.h>

#define N_NODES 50000
#define N_EDGES 1600000
#define F_NODE 64
#define F_EDGE 32
#define MSG 32
// edge_in = 2*F_NODE + F_EDGE = 160, node_in = F_NODE + MSG = 96

// ---------------------------------------------------------------------------
// Edge MLP + scatter: one thread per edge.
//   message = relu([nf[n0] | nf[n1] | ef[e]] @ We + be)   (160 -> 32)
//   atomicAdd into msum[n0][:]
// Weights are read with wave-uniform indices -> scalar loads (SGPRs), so the
// inner loop is pure v_fmac_f32 (VALU-bound, no LDS).
// ---------------------------------------------------------------------------
__global__ __launch_bounds__(256) void edge_mlp_scatter(
    const float* __restrict__ nf,
    const int* __restrict__ eidx,
    const float* __restrict__ ef,
    const float* __restrict__ We,   // [160][32] row-major
    const float* __restrict__ be,   // [32]
    float* __restrict__ msum)       // [N_NODES][32]
{
    const int e = blockIdx.x * 256 + threadIdx.x;   // grid sized exactly
    const int n0 = eidx[e];
    const int n1 = eidx[N_EDGES + e];

    const float4* __restrict__ x0 = reinterpret_cast<const float4*>(nf + (size_t)n0 * F_NODE);
    const float4* __restrict__ x1 = reinterpret_cast<const float4*>(nf + (size_t)n1 * F_NODE);
    const float4* __restrict__ xe = reinterpret_cast<const float4*>(ef + (size_t)e * F_EDGE);

    float acc[MSG];
    #pragma unroll
    for (int j = 0; j < MSG; ++j) acc[j] = be[j];

    // --- segment 0: nf[n0], k = 0..63 ---
    #pragma unroll 2
    for (int c = 0; c < 16; ++c) {
        float4 v = x0[c];
        #pragma unroll
        for (int dk = 0; dk < 4; ++dk) {
            const float xv = (&v.x)[dk];
            const int k = c * 4 + dk;
            #pragma unroll
            for (int j = 0; j < MSG; ++j)
                acc[j] = fmaf(We[k * MSG + j], xv, acc[j]);
        }
    }
    // --- segment 1: nf[n1], k = 64..127 ---
    #pragma unroll 2
    for (int c = 0; c < 16; ++c) {
        float4 v = x1[c];
        #pragma unroll
        for (int dk = 0; dk < 4; ++dk) {
            const float xv = (&v.x)[dk];
            const int k = 64 + c * 4 + dk;
            #pragma unroll
            for (int j = 0; j < MSG; ++j)
                acc[j] = fmaf(We[k * MSG + j], xv, acc[j]);
        }
    }
    // --- segment 2: ef[e], k = 128..159 ---
    #pragma unroll 2
    for (int c = 0; c < 8; ++c) {
        float4 v = xe[c];
        #pragma unroll
        for (int dk = 0; dk < 4; ++dk) {
            const float xv = (&v.x)[dk];
            const int k = 128 + c * 4 + dk;
            #pragma unroll
            for (int j = 0; j < MSG; ++j)
                acc[j] = fmaf(We[k * MSG + j], xv, acc[j]);
        }
    }

    float* __restrict__ dst = msum + (size_t)n0 * MSG;
    #pragma unroll
    for (int j = 0; j < MSG; ++j) {
        const float m = fmaxf(acc[j], 0.0f);
        unsafeAtomicAdd(dst + j, m);   // HW global_atomic_add_f32
    }
}

// ---------------------------------------------------------------------------
// Node MLP: one thread per node.
//   out[n] = relu([nf[n] | msum[n]] @ Wn + bn)   (96 -> 64)
// ---------------------------------------------------------------------------
__global__ __launch_bounds__(256) void node_mlp(
    const float* __restrict__ nf,
    const float* __restrict__ msum,
    const float* __restrict__ Wn,   // [96][64] row-major
    const float* __restrict__ bn,   // [64]
    float* __restrict__ out)        // [N_NODES][64]
{
    const int n = blockIdx.x * 256 + threadIdx.x;
    if (n >= N_NODES) return;

    const float4* __restrict__ x0 = reinterpret_cast<const float4*>(nf + (size_t)n * F_NODE);
    const float4* __restrict__ x1 = reinterpret_cast<const float4*>(msum + (size_t)n * MSG);

    float acc[F_NODE];
    #pragma unroll
    for (int j = 0; j < F_NODE; ++j) acc[j] = bn[j];

    // --- segment 0: nf[n], k = 0..63 ---
    #pragma unroll 2
    for (int c = 0; c < 16; ++c) {
        float4 v = x0[c];
        #pragma unroll
        for (int dk = 0; dk < 4; ++dk) {
            const float xv = (&v.x)[dk];
            const int k = c * 4 + dk;
            #pragma unroll
            for (int j = 0; j < F_NODE; ++j)
                acc[j] = fmaf(Wn[k * F_NODE + j], xv, acc[j]);
        }
    }
    // --- segment 1: msum[n], k = 64..95 ---
    #pragma unroll 2
    for (int c = 0; c < 8; ++c) {
        float4 v = x1[c];
        #pragma unroll
        for (int dk = 0; dk < 4; ++dk) {
            const float xv = (&v.x)[dk];
            const int k = 64 + c * 4 + dk;
            #pragma unroll
            for (int j = 0; j < F_NODE; ++j)
                acc[j] = fmaf(Wn[k * F_NODE + j], xv, acc[j]);
        }
    }

    float4* __restrict__ o = reinterpret_cast<float4*>(out + (size_t)n * F_NODE);
    #pragma unroll
    for (int c = 0; c < 16; ++c) {
        float4 v;
        v.x = fmaxf(acc[c * 4 + 0], 0.0f);
        v.y = fmaxf(acc[c * 4 + 1], 0.0f);
        v.z = fmaxf(acc[c * 4 + 2], 0.0f);
        v.w = fmaxf(acc[c * 4 + 3], 0.0f);
        o[c] = v;
    }
}

extern "C" void kernel_launch(void* const* d_in, const int* in_sizes, int n_in,
                              void* d_out, int out_size, void* d_ws, size_t ws_size,
                              hipStream_t stream) {
    const float* nf = (const float*)d_in[0];
    const int*   ei = (const int*)d_in[1];
    const float* ef = (const float*)d_in[2];
    const float* We = (const float*)d_in[3];
    const float* be = (const float*)d_in[4];
    const float* Wn = (const float*)d_in[5];
    const float* bn = (const float*)d_in[6];
    float* out  = (float*)d_out;
    float* msum = (float*)d_ws;   // [N_NODES][MSG] scratch

    // zero the scatter accumulator every launch (harness does not re-poison)
    hipMemsetAsync(msum, 0, (size_t)N_NODES * MSG * sizeof(float), stream);

    edge_mlp_scatter<<<N_EDGES / 256, 256, 0, stream>>>(nf, ei, ef, We, be, msum);
    node_mlp<<<(N_NODES + 255) / 256, 256, 0, stream>>>(nf, msum, Wn, bn, out);
}

// Round 2
// 641.669 us; speedup vs baseline: 4.2585x; 4.2585x over previous
//
#include <hip/hip_runtime.h>

#define N_NODES 50000
#define N_EDGES 1600000
#define F_NODE 64
#define F_EDGE 32
#define MSG 32
// edge_in = 2*F_NODE + F_EDGE = 160, node_in = F_NODE + MSG = 96

// ===========================================================================
// Sorted-scatter path: hist -> scan -> edge MLP (write to CSR slot) -> gather
// ===========================================================================

// Phase 1: histogram of source nodes. 1.6M fire-and-forget int atomics.
__global__ __launch_bounds__(256) void hist_kernel(
    const int* __restrict__ eidx, int* __restrict__ cnt)
{
    const int e = blockIdx.x * 256 + threadIdx.x;   // grid exact
    atomicAdd(&cnt[eidx[e]], 1);
}

// Phase 2: single-block exclusive scan of cnt[N_NODES] -> base[N_NODES+1],
// and re-init cnt (aliased as cursor) to the base offsets.
__global__ __launch_bounds__(1024) void scan_kernel(
    int* __restrict__ cnt_cursor, int* __restrict__ base)
{
    __shared__ int part[1024];
    const int t = threadIdx.x;
    const int CH = (N_NODES + 1023) / 1024;   // 49
    const int lo = t * CH;
    const int hi = min(lo + CH, N_NODES);
    int s = 0;
    for (int i = lo; i < hi; ++i) s += cnt_cursor[i];
    part[t] = s;
    __syncthreads();
    // Hillis-Steele inclusive scan (read-all then write, barrier-separated)
    for (int off = 1; off < 1024; off <<= 1) {
        int u = (t >= off) ? part[t - off] : 0;
        __syncthreads();
        part[t] += u;
        __syncthreads();
    }
    int run = part[t] - s;   // exclusive prefix of this chunk
    for (int i = lo; i < hi; ++i) {
        int c = cnt_cursor[i];
        base[i] = run;
        cnt_cursor[i] = run;   // cursor init
        run += c;
    }
    if (t == 1023) base[N_NODES] = part[1023];   // total = N_EDGES
}

// Phase 3: edge MLP, message written once to its CSR slot.
__global__ __launch_bounds__(256) void edge_mlp_sorted(
    const float* __restrict__ nf,
    const int* __restrict__ eidx,
    const float* __restrict__ ef,
    const float* __restrict__ We,   // [160][32] row-major
    const float* __restrict__ be,   // [32]
    int* __restrict__ cursor,
    float* __restrict__ msg)        // [N_EDGES][32], segment-sorted
{
    const int e = blockIdx.x * 256 + threadIdx.x;   // grid exact
    const int n0 = eidx[e];
    const int n1 = eidx[N_EDGES + e];
    // position atomic issued EARLY: its round-trip hides under the MLP chain
    const int pos = atomicAdd(&cursor[n0], 1);

    const float4* __restrict__ x0 = reinterpret_cast<const float4*>(nf + (size_t)n0 * F_NODE);
    const float4* __restrict__ x1 = reinterpret_cast<const float4*>(nf + (size_t)n1 * F_NODE);
    const float4* __restrict__ xe = reinterpret_cast<const float4*>(ef + (size_t)e * F_EDGE);

    float acc[MSG];
    #pragma unroll
    for (int j = 0; j < MSG; ++j) acc[j] = be[j];

    #pragma unroll 2
    for (int c = 0; c < 16; ++c) {
        float4 v = x0[c];
        #pragma unroll
        for (int dk = 0; dk < 4; ++dk) {
            const float xv = (&v.x)[dk];
            const int k = c * 4 + dk;
            #pragma unroll
            for (int j = 0; j < MSG; ++j)
                acc[j] = fmaf(We[k * MSG + j], xv, acc[j]);
        }
    }
    #pragma unroll 2
    for (int c = 0; c < 16; ++c) {
        float4 v = x1[c];
        #pragma unroll
        for (int dk = 0; dk < 4; ++dk) {
            const float xv = (&v.x)[dk];
            const int k = 64 + c * 4 + dk;
            #pragma unroll
            for (int j = 0; j < MSG; ++j)
                acc[j] = fmaf(We[k * MSG + j], xv, acc[j]);
        }
    }
    #pragma unroll 2
    for (int c = 0; c < 8; ++c) {
        float4 v = xe[c];
        #pragma unroll
        for (int dk = 0; dk < 4; ++dk) {
            const float xv = (&v.x)[dk];
            const int k = 128 + c * 4 + dk;
            #pragma unroll
            for (int j = 0; j < MSG; ++j)
                acc[j] = fmaf(We[k * MSG + j], xv, acc[j]);
        }
    }

    float4* __restrict__ dst = reinterpret_cast<float4*>(msg + (size_t)pos * MSG);
    #pragma unroll
    for (int c = 0; c < 8; ++c) {
        float4 o;
        o.x = fmaxf(acc[c * 4 + 0], 0.0f);
        o.y = fmaxf(acc[c * 4 + 1], 0.0f);
        o.z = fmaxf(acc[c * 4 + 2], 0.0f);
        o.w = fmaxf(acc[c * 4 + 3], 0.0f);
        dst[c] = o;
    }
}

// Phase 4: wave-per-node segmented sum + node MLP.
__global__ __launch_bounds__(256) void node_agg_mlp(
    const float* __restrict__ nf,
    const float* __restrict__ msg,
    const int* __restrict__ base,
    const float* __restrict__ Wn,   // [96][64] row-major
    const float* __restrict__ bn,   // [64]
    float* __restrict__ out)        // [N_NODES][64]
{
    __shared__ float xbuf[4][96];
    const int lane = threadIdx.x & 63;
    const int w    = threadIdx.x >> 6;
    int n = blockIdx.x * 4 + w;                     // grid exact: 50000/4
    n = __builtin_amdgcn_readfirstlane(n);          // force scalar (s_load row)

    const int start = base[n];
    const int end   = base[n + 1];

    // segmented sum: lanes 0..31 = even rows, 32..63 = odd rows; component lane&31
    const int c = lane & 31;
    float s = 0.0f;
    for (int i = start + (lane >> 5); i < end; i += 2)
        s += msg[(size_t)i * MSG + c];
    s += __shfl_xor(s, 32, 64);   // both halves now hold the component total

    // stage x[96] = [nf[n] | msum] in LDS
    float* xb = xbuf[w];
    xb[lane] = nf[(size_t)n * F_NODE + lane];
    if (lane < 32) xb[F_NODE + lane] = s;
    __syncthreads();

    // lane computes output component `lane`
    float acc = bn[lane];
    #pragma unroll 8
    for (int k = 0; k < F_NODE + MSG; ++k)
        acc = fmaf(Wn[k * F_NODE + lane], xb[k], acc);

    out[(size_t)n * F_NODE + lane] = fmaxf(acc, 0.0f);
}

// ===========================================================================
// Fallback path (round-1, proven): direct f32 atomic scatter
// ===========================================================================
__global__ __launch_bounds__(256) void edge_mlp_atomic(
    const float* __restrict__ nf, const int* __restrict__ eidx,
    const float* __restrict__ ef, const float* __restrict__ We,
    const float* __restrict__ be, float* __restrict__ msum)
{
    const int e = blockIdx.x * 256 + threadIdx.x;
    const int n0 = eidx[e];
    const int n1 = eidx[N_EDGES + e];
    const float4* x0 = reinterpret_cast<const float4*>(nf + (size_t)n0 * F_NODE);
    const float4* x1 = reinterpret_cast<const float4*>(nf + (size_t)n1 * F_NODE);
    const float4* xe = reinterpret_cast<const float4*>(ef + (size_t)e * F_EDGE);
    float acc[MSG];
    #pragma unroll
    for (int j = 0; j < MSG; ++j) acc[j] = be[j];
    #pragma unroll 2
    for (int c = 0; c < 16; ++c) {
        float4 v = x0[c];
        #pragma unroll
        for (int dk = 0; dk < 4; ++dk) {
            const float xv = (&v.x)[dk]; const int k = c * 4 + dk;
            #pragma unroll
            for (int j = 0; j < MSG; ++j) acc[j] = fmaf(We[k * MSG + j], xv, acc[j]);
        }
    }
    #pragma unroll 2
    for (int c = 0; c < 16; ++c) {
        float4 v = x1[c];
        #pragma unroll
        for (int dk = 0; dk < 4; ++dk) {
            const float xv = (&v.x)[dk]; const int k = 64 + c * 4 + dk;
            #pragma unroll
            for (int j = 0; j < MSG; ++j) acc[j] = fmaf(We[k * MSG + j], xv, acc[j]);
        }
    }
    #pragma unroll 2
    for (int c = 0; c < 8; ++c) {
        float4 v = xe[c];
        #pragma unroll
        for (int dk = 0; dk < 4; ++dk) {
            const float xv = (&v.x)[dk]; const int k = 128 + c * 4 + dk;
            #pragma unroll
            for (int j = 0; j < MSG; ++j) acc[j] = fmaf(We[k * MSG + j], xv, acc[j]);
        }
    }
    float* dst = msum + (size_t)n0 * MSG;
    #pragma unroll
    for (int j = 0; j < MSG; ++j) unsafeAtomicAdd(dst + j, fmaxf(acc[j], 0.0f));
}

__global__ __launch_bounds__(256) void node_mlp_thread(
    const float* __restrict__ nf, const float* __restrict__ msum,
    const float* __restrict__ Wn, const float* __restrict__ bn,
    float* __restrict__ out)
{
    const int n = blockIdx.x * 256 + threadIdx.x;
    if (n >= N_NODES) return;
    const float4* x0 = reinterpret_cast<const float4*>(nf + (size_t)n * F_NODE);
    const float4* x1 = reinterpret_cast<const float4*>(msum + (size_t)n * MSG);
    float acc[F_NODE];
    #pragma unroll
    for (int j = 0; j < F_NODE; ++j) acc[j] = bn[j];
    #pragma unroll 2
    for (int c = 0; c < 16; ++c) {
        float4 v = x0[c];
        #pragma unroll
        for (int dk = 0; dk < 4; ++dk) {
            const float xv = (&v.x)[dk]; const int k = c * 4 + dk;
            #pragma unroll
            for (int j = 0; j < F_NODE; ++j) acc[j] = fmaf(Wn[k * F_NODE + j], xv, acc[j]);
        }
    }
    #pragma unroll 2
    for (int c = 0; c < 8; ++c) {
        float4 v = x1[c];
        #pragma unroll
        for (int dk = 0; dk < 4; ++dk) {
            const float xv = (&v.x)[dk]; const int k = 64 + c * 4 + dk;
            #pragma unroll
            for (int j = 0; j < F_NODE; ++j) acc[j] = fmaf(Wn[k * F_NODE + j], xv, acc[j]);
        }
    }
    float4* o = reinterpret_cast<float4*>(out + (size_t)n * F_NODE);
    #pragma unroll
    for (int cc = 0; cc < 16; ++cc) {
        float4 v;
        v.x = fmaxf(acc[cc * 4 + 0], 0.0f);
        v.y = fmaxf(acc[cc * 4 + 1], 0.0f);
        v.z = fmaxf(acc[cc * 4 + 2], 0.0f);
        v.w = fmaxf(acc[cc * 4 + 3], 0.0f);
        o[cc] = v;
    }
}

// ===========================================================================
extern "C" void kernel_launch(void* const* d_in, const int* in_sizes, int n_in,
                              void* d_out, int out_size, void* d_ws, size_t ws_size,
                              hipStream_t stream) {
    const float* nf = (const float*)d_in[0];
    const int*   ei = (const int*)d_in[1];
    const float* ef = (const float*)d_in[2];
    const float* We = (const float*)d_in[3];
    const float* be = (const float*)d_in[4];
    const float* Wn = (const float*)d_in[5];
    const float* bn = (const float*)d_in[6];
    float* out = (float*)d_out;

    const size_t msg_elems = (size_t)N_EDGES * MSG;
    const size_t need = msg_elems * sizeof(float) + (size_t)(2 * N_NODES + 2) * sizeof(int);

    if (ws_size >= need) {
        float* msg  = (float*)d_ws;                       // [E][32]
        int* base   = (int*)(msg + msg_elems);            // [N+1]
        int* cursor = base + (N_NODES + 1);               // [N]

        hipMemsetAsync(cursor, 0, (size_t)N_NODES * sizeof(int), stream);
        hist_kernel<<<N_EDGES / 256, 256, 0, stream>>>(ei, cursor);
        scan_kernel<<<1, 1024, 0, stream>>>(cursor, base);
        edge_mlp_sorted<<<N_EDGES / 256, 256, 0, stream>>>(nf, ei, ef, We, be, cursor, msg);
        node_agg_mlp<<<N_NODES / 4, 256, 0, stream>>>(nf, msg, base, Wn, bn, out);
    } else {
        float* msum = (float*)d_ws;   // [N][32]
        hipMemsetAsync(msum, 0, (size_t)N_NODES * MSG * sizeof(float), stream);
        edge_mlp_atomic<<<N_EDGES / 256, 256, 0, stream>>>(nf, ei, ef, We, be, msum);
        node_mlp_thread<<<(N_NODES + 255) / 256, 256, 0, stream>>>(nf, msum, Wn, bn, out);
    }
}

// Round 4
// 552.452 us; speedup vs baseline: 4.9462x; 1.1615x over previous
//
#include <hip/hip_runtime.h>

#define N_NODES 50000
#define N_EDGES 1600000
#define F_NODE 64
#define F_EDGE 32
#define MSG 32
// edge_in = 2*F_NODE + F_EDGE = 160, node_in = F_NODE + MSG = 96

// ---------------------------------------------------------------------------
// helpers: bf16 pack/unpack (RNE; data has no NaN)
// ---------------------------------------------------------------------------
__device__ __forceinline__ unsigned short f2bf(float f) {
    unsigned u = __float_as_uint(f);
    return (unsigned short)((u + 0x7FFFu + ((u >> 16) & 1u)) >> 16);
}
__device__ __forceinline__ float bf_lo(unsigned w) { return __uint_as_float(w << 16); }
__device__ __forceinline__ float bf_hi(unsigned w) { return __uint_as_float(w & 0xFFFF0000u); }

// ---------------------------------------------------------------------------
// Phase 0: nf (fp32) -> nfb (bf16)
// ---------------------------------------------------------------------------
__global__ __launch_bounds__(256) void conv_nf(
    const float* __restrict__ nf, unsigned short* __restrict__ nfb)
{
    const int i = (blockIdx.x * 256 + threadIdx.x) * 8;
    if (i >= N_NODES * F_NODE) return;
    const float4 a = *reinterpret_cast<const float4*>(nf + i);
    const float4 b = *reinterpret_cast<const float4*>(nf + i + 4);
    uint4 o;
    o.x = (unsigned)f2bf(a.x) | ((unsigned)f2bf(a.y) << 16);
    o.y = (unsigned)f2bf(a.z) | ((unsigned)f2bf(a.w) << 16);
    o.z = (unsigned)f2bf(b.x) | ((unsigned)f2bf(b.y) << 16);
    o.w = (unsigned)f2bf(b.z) | ((unsigned)f2bf(b.w) << 16);
    *reinterpret_cast<uint4*>(nfb + i) = o;
}

// ---------------------------------------------------------------------------
// Phase 1: histogram of source nodes
// ---------------------------------------------------------------------------
__global__ __launch_bounds__(256) void hist_kernel(
    const int* __restrict__ eidx, int* __restrict__ cnt)
{
    const int e = blockIdx.x * 256 + threadIdx.x;   // grid exact
    atomicAdd(&cnt[eidx[e]], 1);
}

// ---------------------------------------------------------------------------
// Phase 2: single-block exclusive scan cnt -> base; cnt becomes cursor
// ---------------------------------------------------------------------------
__global__ __launch_bounds__(1024) void scan_kernel(
    int* __restrict__ cnt_cursor, int* __restrict__ base)
{
    __shared__ int part[1024];
    const int t = threadIdx.x;
    const int CH = (N_NODES + 1023) / 1024;   // 49
    const int lo = t * CH;
    const int hi = min(lo + CH, N_NODES);
    int s = 0;
    for (int i = lo; i < hi; ++i) s += cnt_cursor[i];
    part[t] = s;
    __syncthreads();
    for (int off = 1; off < 1024; off <<= 1) {
        int u = (t >= off) ? part[t - off] : 0;
        __syncthreads();
        part[t] += u;
        __syncthreads();
    }
    int run = part[t] - s;
    for (int i = lo; i < hi; ++i) {
        int c = cnt_cursor[i];
        base[i] = run;
        cnt_cursor[i] = run;
        run += c;
    }
    if (t == 1023) base[N_NODES] = part[1023];
}

// ---------------------------------------------------------------------------
// Phase 3: scatter edge metadata into CSR slot order
// ---------------------------------------------------------------------------
__global__ __launch_bounds__(256) void perm_kernel(
    const int* __restrict__ eidx, int* __restrict__ cursor,
    int4* __restrict__ perm)
{
    const int e = blockIdx.x * 256 + threadIdx.x;   // grid exact
    const int n0 = eidx[e];
    const int n1 = eidx[N_EDGES + e];
    const int pos = atomicAdd(&cursor[n0], 1);
    perm[pos] = make_int4(n0, n1, e, 0);
}

// ---------------------------------------------------------------------------
// Phase 4: edge MLP in CSR order; msg[slot] written sequentially (bf16).
// x0/x1 gathered from bf16 nfb (half the bytes); ef/We/accum stay fp32.
// ---------------------------------------------------------------------------
__global__ __launch_bounds__(256) void edge_mlp_csr(
    const unsigned short* __restrict__ nfb,
    const int4* __restrict__ perm,
    const float* __restrict__ ef,
    const float* __restrict__ We,   // [160][32] row-major
    const float* __restrict__ be,   // [32]
    unsigned short* __restrict__ msgb)  // [N_EDGES][32] bf16, CSR slot order
{
    const int slot = blockIdx.x * 256 + threadIdx.x;   // grid exact
    const int4 p = perm[slot];
    const int n0 = p.x;
    const int n1 = p.y;
    const int e  = p.z;

    const uint4* __restrict__ x0 = reinterpret_cast<const uint4*>(nfb + (size_t)n0 * F_NODE);
    const uint4* __restrict__ x1 = reinterpret_cast<const uint4*>(nfb + (size_t)n1 * F_NODE);
    const float4* __restrict__ xe = reinterpret_cast<const float4*>(ef + (size_t)e * F_EDGE);

    float acc[MSG];
    #pragma unroll
    for (int j = 0; j < MSG; ++j) acc[j] = be[j];

    // k = 0..63 : nfb[n0]  (run-local -> L1 hit)
    #pragma unroll 2
    for (int c = 0; c < 8; ++c) {
        const uint4 v = x0[c];
        const unsigned wv[4] = {v.x, v.y, v.z, v.w};
        #pragma unroll
        for (int t = 0; t < 4; ++t) {
            const float f0 = bf_lo(wv[t]);
            const float f1 = bf_hi(wv[t]);
            const int k = c * 8 + t * 2;
            #pragma unroll
            for (int j = 0; j < MSG; ++j) acc[j] = fmaf(We[k * MSG + j], f0, acc[j]);
            #pragma unroll
            for (int j = 0; j < MSG; ++j) acc[j] = fmaf(We[(k + 1) * MSG + j], f1, acc[j]);
        }
    }
    // k = 64..127 : nfb[n1]  (random gather, 128B rows)
    #pragma unroll 2
    for (int c = 0; c < 8; ++c) {
        const uint4 v = x1[c];
        const unsigned wv[4] = {v.x, v.y, v.z, v.w};
        #pragma unroll
        for (int t = 0; t < 4; ++t) {
            const float f0 = bf_lo(wv[t]);
            const float f1 = bf_hi(wv[t]);
            const int k = 64 + c * 8 + t * 2;
            #pragma unroll
            for (int j = 0; j < MSG; ++j) acc[j] = fmaf(We[k * MSG + j], f0, acc[j]);
            #pragma unroll
            for (int j = 0; j < MSG; ++j) acc[j] = fmaf(We[(k + 1) * MSG + j], f1, acc[j]);
        }
    }
    // k = 128..159 : ef[e]  (fp32, random 128B rows)
    #pragma unroll 2
    for (int c = 0; c < 8; ++c) {
        const float4 v = xe[c];
        #pragma unroll
        for (int dk = 0; dk < 4; ++dk) {
            const float xv = (&v.x)[dk];
            const int k = 128 + c * 4 + dk;
            #pragma unroll
            for (int j = 0; j < MSG; ++j) acc[j] = fmaf(We[k * MSG + j], xv, acc[j]);
        }
    }

    // ReLU + pack to bf16, sequential 64B store
    uint4* __restrict__ dst = reinterpret_cast<uint4*>(msgb + (size_t)slot * MSG);
    #pragma unroll
    for (int c = 0; c < 4; ++c) {
        uint4 o;
        o.x = (unsigned)f2bf(fmaxf(acc[c*8+0],0.f)) | ((unsigned)f2bf(fmaxf(acc[c*8+1],0.f)) << 16);
        o.y = (unsigned)f2bf(fmaxf(acc[c*8+2],0.f)) | ((unsigned)f2bf(fmaxf(acc[c*8+3],0.f)) << 16);
        o.z = (unsigned)f2bf(fmaxf(acc[c*8+4],0.f)) | ((unsigned)f2bf(fmaxf(acc[c*8+5],0.f)) << 16);
        o.w = (unsigned)f2bf(fmaxf(acc[c*8+6],0.f)) | ((unsigned)f2bf(fmaxf(acc[c*8+7],0.f)) << 16);
        dst[c] = o;
    }
}

// ---------------------------------------------------------------------------
// Phase 5: wave-per-node segmented sum (vectorized bf16 reads) + node MLP.
// lane = r*4+q : r in [0,16) row within stripe, q in [0,4) uint4 within row.
// ---------------------------------------------------------------------------
__global__ __launch_bounds__(256) void node_agg_mlp(
    const float* __restrict__ nf,
    const unsigned short* __restrict__ msgb,
    const int* __restrict__ base,
    const float* __restrict__ Wn,   // [96][64] row-major
    const float* __restrict__ bn,   // [64]
    float* __restrict__ out)        // [N_NODES][64]
{
    __shared__ float xbuf[4][96];
    const int lane = threadIdx.x & 63;
    const int w    = threadIdx.x >> 6;
    int n = blockIdx.x * 4 + w;                    // grid exact: 50000/4
    n = __builtin_amdgcn_readfirstlane(n);

    const int start = base[n];
    const int end   = base[n + 1];
    const int r = lane >> 2;        // 0..15
    const int q = lane & 3;         // 0..3

    float part[8];
    #pragma unroll
    for (int i = 0; i < 8; ++i) part[i] = 0.0f;

    for (int i = start + r; i < end; i += 16) {
        const uint4 v = reinterpret_cast<const uint4*>(msgb + (size_t)i * MSG)[q];
        part[0] += bf_lo(v.x); part[1] += bf_hi(v.x);
        part[2] += bf_lo(v.y); part[3] += bf_hi(v.y);
        part[4] += bf_lo(v.z); part[5] += bf_hi(v.z);
        part[6] += bf_lo(v.w); part[7] += bf_hi(v.w);
    }
    // reduce across r (lanes with equal q): xor deltas 4,8,16,32
    #pragma unroll
    for (int d = 4; d < 64; d <<= 1) {
        #pragma unroll
        for (int i = 0; i < 8; ++i) part[i] += __shfl_xor(part[i], d, 64);
    }

    // stage x[96] = [nf[n] fp32 | msum] in LDS
    float* xb = xbuf[w];
    xb[lane] = nf[(size_t)n * F_NODE + lane];
    if (r == 0) {
        #pragma unroll
        for (int i = 0; i < 8; ++i) xb[F_NODE + q * 8 + i] = part[i];
    }
    __syncthreads();

    // lane computes output component `lane`
    float acc = bn[lane];
    #pragma unroll 8
    for (int k = 0; k < F_NODE + MSG; ++k)
        acc = fmaf(Wn[k * F_NODE + lane], xb[k], acc);

    out[(size_t)n * F_NODE + lane] = fmaxf(acc, 0.0f);
}

// ===========================================================================
// Fallback (round-1, proven): direct f32 atomic scatter + thread-per-node MLP
// ===========================================================================
__global__ __launch_bounds__(256) void edge_mlp_atomic(
    const float* __restrict__ nf, const int* __restrict__ eidx,
    const float* __restrict__ ef, const float* __restrict__ We,
    const float* __restrict__ be, float* __restrict__ msum)
{
    const int e = blockIdx.x * 256 + threadIdx.x;
    const int n0 = eidx[e];
    const int n1 = eidx[N_EDGES + e];
    const float4* x0 = reinterpret_cast<const float4*>(nf + (size_t)n0 * F_NODE);
    const float4* x1 = reinterpret_cast<const float4*>(nf + (size_t)n1 * F_NODE);
    const float4* xe = reinterpret_cast<const float4*>(ef + (size_t)e * F_EDGE);
    float acc[MSG];
    #pragma unroll
    for (int j = 0; j < MSG; ++j) acc[j] = be[j];
    #pragma unroll 2
    for (int c = 0; c < 16; ++c) {
        float4 v = x0[c];
        #pragma unroll
        for (int dk = 0; dk < 4; ++dk) {
            const float xv = (&v.x)[dk]; const int k = c * 4 + dk;
            #pragma unroll
            for (int j = 0; j < MSG; ++j) acc[j] = fmaf(We[k * MSG + j], xv, acc[j]);
        }
    }
    #pragma unroll 2
    for (int c = 0; c < 16; ++c) {
        float4 v = x1[c];
        #pragma unroll
        for (int dk = 0; dk < 4; ++dk) {
            const float xv = (&v.x)[dk]; const int k = 64 + c * 4 + dk;
            #pragma unroll
            for (int j = 0; j < MSG; ++j) acc[j] = fmaf(We[k * MSG + j], xv, acc[j]);
        }
    }
    #pragma unroll 2
    for (int c = 0; c < 8; ++c) {
        float4 v = xe[c];
        #pragma unroll
        for (int dk = 0; dk < 4; ++dk) {
            const float xv = (&v.x)[dk]; const int k = 128 + c * 4 + dk;
            #pragma unroll
            for (int j = 0; j < MSG; ++j) acc[j] = fmaf(We[k * MSG + j], xv, acc[j]);
        }
    }
    float* dst = msum + (size_t)n0 * MSG;
    #pragma unroll
    for (int j = 0; j < MSG; ++j) unsafeAtomicAdd(dst + j, fmaxf(acc[j], 0.0f));
}

__global__ __launch_bounds__(256) void node_mlp_thread(
    const float* __restrict__ nf, const float* __restrict__ msum,
    const float* __restrict__ Wn, const float* __restrict__ bn,
    float* __restrict__ out)
{
    const int n = blockIdx.x * 256 + threadIdx.x;
    if (n >= N_NODES) return;
    const float4* x0 = reinterpret_cast<const float4*>(nf + (size_t)n * F_NODE);
    const float4* x1 = reinterpret_cast<const float4*>(msum + (size_t)n * MSG);
    float acc[F_NODE];
    #pragma unroll
    for (int j = 0; j < F_NODE; ++j) acc[j] = bn[j];
    #pragma unroll 2
    for (int c = 0; c < 16; ++c) {
        float4 v = x0[c];
        #pragma unroll
        for (int dk = 0; dk < 4; ++dk) {
            const float xv = (&v.x)[dk]; const int k = c * 4 + dk;
            #pragma unroll
            for (int j = 0; j < F_NODE; ++j) acc[j] = fmaf(Wn[k * F_NODE + j], xv, acc[j]);
        }
    }
    #pragma unroll 2
    for (int c = 0; c < 8; ++c) {
        float4 v = x1[c];
        #pragma unroll
        for (int dk = 0; dk < 4; ++dk) {
            const float xv = (&v.x)[dk]; const int k = 64 + c * 4 + dk;
            #pragma unroll
            for (int j = 0; j < F_NODE; ++j) acc[j] = fmaf(Wn[k * F_NODE + j], xv, acc[j]);
        }
    }
    float4* o = reinterpret_cast<float4*>(out + (size_t)n * F_NODE);
    #pragma unroll
    for (int cc = 0; cc < 16; ++cc) {
        float4 v;
        v.x = fmaxf(acc[cc * 4 + 0], 0.0f);
        v.y = fmaxf(acc[cc * 4 + 1], 0.0f);
        v.z = fmaxf(acc[cc * 4 + 2], 0.0f);
        v.w = fmaxf(acc[cc * 4 + 3], 0.0f);
        o[cc] = v;
    }
}

// ===========================================================================
extern "C" void kernel_launch(void* const* d_in, const int* in_sizes, int n_in,
                              void* d_out, int out_size, void* d_ws, size_t ws_size,
                              hipStream_t stream) {
    const float* nf = (const float*)d_in[0];
    const int*   ei = (const int*)d_in[1];
    const float* ef = (const float*)d_in[2];
    const float* We = (const float*)d_in[3];
    const float* be = (const float*)d_in[4];
    const float* Wn = (const float*)d_in[5];
    const float* bn = (const float*)d_in[6];
    float* out = (float*)d_out;

    // ws layout: [msgb bf16 E*32][base i32 N+1][cursor i32 N][pad16][nfb bf16 N*64][pad16][perm int4 E]
    size_t off_base   = (size_t)N_EDGES * MSG * sizeof(unsigned short);        // 102.4 MB
    size_t off_cursor = off_base + (size_t)(N_NODES + 1) * sizeof(int);
    size_t off_nfb    = (off_cursor + (size_t)N_NODES * sizeof(int) + 15) & ~(size_t)15;
    size_t off_perm   = (off_nfb + (size_t)N_NODES * F_NODE * sizeof(unsigned short) + 15) & ~(size_t)15;
    const size_t need = off_perm + (size_t)N_EDGES * sizeof(int4);             // ~134.8 MB

    if (ws_size >= need) {
        char* ws = (char*)d_ws;
        unsigned short* msgb  = (unsigned short*)ws;
        int*            basep = (int*)(ws + off_base);
        int*            cursor= (int*)(ws + off_cursor);
        unsigned short* nfb   = (unsigned short*)(ws + off_nfb);
        int4*           perm  = (int4*)(ws + off_perm);

        hipMemsetAsync(cursor, 0, (size_t)N_NODES * sizeof(int), stream);
        conv_nf<<<(N_NODES * F_NODE / 8 + 255) / 256, 256, 0, stream>>>(nf, nfb);
        hist_kernel<<<N_EDGES / 256, 256, 0, stream>>>(ei, cursor);
        scan_kernel<<<1, 1024, 0, stream>>>(cursor, basep);
        perm_kernel<<<N_EDGES / 256, 256, 0, stream>>>(ei, cursor, perm);
        edge_mlp_csr<<<N_EDGES / 256, 256, 0, stream>>>(nfb, perm, ef, We, be, msgb);
        node_agg_mlp<<<N_NODES / 4, 256, 0, stream>>>(nf, msgb, basep, Wn, bn, out);
    } else {
        float* msum = (float*)d_ws;
        hipMemsetAsync(msum, 0, (size_t)N_NODES * MSG * sizeof(float), stream);
        edge_mlp_atomic<<<N_EDGES / 256, 256, 0, stream>>>(nf, ei, ef, We, be, msum);
        node_mlp_thread<<<(N_NODES + 255) / 256, 256, 0, stream>>>(nf, msum, Wn, bn, out);
    }
}

// Round 5
// 480.786 us; speedup vs baseline: 5.6834x; 1.1491x over previous
//
#include <hip/hip_runtime.h>

#define N_NODES 50000
#define N_EDGES 1600000
#define F_NODE 64
#define F_EDGE 32
#define MSG 32
#define EDGE_IN 160                       // 2*F_NODE + F_EDGE
#define NF_ELEMS (N_NODES * F_NODE)       // 3,200,000
#define WE_ELEMS (EDGE_IN * MSG)          // 5,120

typedef __attribute__((ext_vector_type(8))) short short8_t;   // 8 bf16
typedef __attribute__((ext_vector_type(4))) float f32x4_t;    // MFMA acc

// ---------------------------------------------------------------------------
// bf16 helpers (RNE)
// ---------------------------------------------------------------------------
__device__ __forceinline__ unsigned short f2bf(float f) {
    unsigned u = __float_as_uint(f);
    return (unsigned short)((u + 0x7FFFu + ((u >> 16) & 1u)) >> 16);
}
__device__ __forceinline__ float bf_lo(unsigned w) { return __uint_as_float(w << 16); }
__device__ __forceinline__ float bf_hi(unsigned w) { return __uint_as_float(w & 0xFFFF0000u); }

// ---------------------------------------------------------------------------
// Phase 0: nf (fp32) -> nfb (bf16), We (fp32) -> Webb (bf16)
// ---------------------------------------------------------------------------
__global__ __launch_bounds__(256) void conv_all(
    const float* __restrict__ nf, const float* __restrict__ We,
    unsigned short* __restrict__ nfb, unsigned short* __restrict__ Webb)
{
    const int i = (blockIdx.x * 256 + threadIdx.x) * 8;
    if (i < NF_ELEMS) {
        const float4 a = *reinterpret_cast<const float4*>(nf + i);
        const float4 b = *reinterpret_cast<const float4*>(nf + i + 4);
        uint4 o;
        o.x = (unsigned)f2bf(a.x) | ((unsigned)f2bf(a.y) << 16);
        o.y = (unsigned)f2bf(a.z) | ((unsigned)f2bf(a.w) << 16);
        o.z = (unsigned)f2bf(b.x) | ((unsigned)f2bf(b.y) << 16);
        o.w = (unsigned)f2bf(b.z) | ((unsigned)f2bf(b.w) << 16);
        *reinterpret_cast<uint4*>(nfb + i) = o;
    } else if (i < NF_ELEMS + WE_ELEMS) {
        const int j = i - NF_ELEMS;
        const float4 a = *reinterpret_cast<const float4*>(We + j);
        const float4 b = *reinterpret_cast<const float4*>(We + j + 4);
        uint4 o;
        o.x = (unsigned)f2bf(a.x) | ((unsigned)f2bf(a.y) << 16);
        o.y = (unsigned)f2bf(a.z) | ((unsigned)f2bf(a.w) << 16);
        o.z = (unsigned)f2bf(b.x) | ((unsigned)f2bf(b.y) << 16);
        o.w = (unsigned)f2bf(b.z) | ((unsigned)f2bf(b.w) << 16);
        *reinterpret_cast<uint4*>(Webb + j) = o;
    }
}

// ---------------------------------------------------------------------------
// Phase 1: histogram of source nodes  (proven)
// ---------------------------------------------------------------------------
__global__ __launch_bounds__(256) void hist_kernel(
    const int* __restrict__ eidx, int* __restrict__ cnt)
{
    const int e = blockIdx.x * 256 + threadIdx.x;   // grid exact
    atomicAdd(&cnt[eidx[e]], 1);
}

// ---------------------------------------------------------------------------
// Phase 2: single-block exclusive scan cnt -> base; cnt becomes cursor (proven)
// ---------------------------------------------------------------------------
__global__ __launch_bounds__(1024) void scan_kernel(
    int* __restrict__ cnt_cursor, int* __restrict__ base)
{
    __shared__ int part[1024];
    const int t = threadIdx.x;
    const int CH = (N_NODES + 1023) / 1024;   // 49
    const int lo = t * CH;
    const int hi = min(lo + CH, N_NODES);
    int s = 0;
    for (int i = lo; i < hi; ++i) s += cnt_cursor[i];
    part[t] = s;
    __syncthreads();
    for (int off = 1; off < 1024; off <<= 1) {
        int u = (t >= off) ? part[t - off] : 0;
        __syncthreads();
        part[t] += u;
        __syncthreads();
    }
    int run = part[t] - s;
    for (int i = lo; i < hi; ++i) {
        int c = cnt_cursor[i];
        base[i] = run;
        cnt_cursor[i] = run;
        run += c;
    }
    if (t == 1023) base[N_NODES] = part[1023];
}

// ---------------------------------------------------------------------------
// Phase 3: scatter edge metadata into CSR slot order  (proven)
// ---------------------------------------------------------------------------
__global__ __launch_bounds__(256) void perm_kernel(
    const int* __restrict__ eidx, int* __restrict__ cursor,
    int4* __restrict__ perm)
{
    const int e = blockIdx.x * 256 + threadIdx.x;   // grid exact
    const int n0 = eidx[e];
    const int n1 = eidx[N_EDGES + e];
    const int pos = atomicAdd(&cursor[n0], 1);
    perm[pos] = make_int4(n0, n1, e, 0);
}

// ---------------------------------------------------------------------------
// Phase 4: edge MLP via MFMA. M-tile = 16 CSR slots, N = 32 (two 16x16 tiles),
// K = 160 (5 steps of 32).
//  A-frag (per lane): row = l&15 (edge in tile), k = (l>>4)*8 + j
//  B-frag (per lane): col = l&15, same k                (Webb wave-preloaded)
//  C/D   (verified m89): col = l&15, row = (l>>4)*4 + reg
// C goes through 1KB per-wave LDS to produce coalesced 16B msgb stores.
// ---------------------------------------------------------------------------
__global__ __launch_bounds__(256) void edge_mlp_mfma(
    const unsigned short* __restrict__ nfb,
    const int4* __restrict__ perm,
    const float* __restrict__ ef,
    const unsigned short* __restrict__ Webb,   // [160][32] bf16 row-major
    const float* __restrict__ be,              // [32] fp32
    unsigned short* __restrict__ msgb)         // [N_EDGES][32] bf16, CSR order
{
    __shared__ unsigned short cbuf[4][16 * MSG];   // per-wave private 1KB
    const int l   = threadIdx.x & 63;
    const int w   = threadIdx.x >> 6;
    const int col = l & 15;
    const int g   = l >> 4;

    // ---- B fragments: 5 K-steps x 2 N-tiles, loaded once per wave ----
    short8_t bfrag[5][2];
    #pragma unroll
    for (int s = 0; s < 5; ++s) {
        #pragma unroll
        for (int t = 0; t < 2; ++t) {
            short8_t v;
            #pragma unroll
            for (int j = 0; j < 8; ++j)
                v[j] = (short)Webb[s * 1024 + g * 256 + j * 32 + t * 16 + col];
            bfrag[s][t] = v;
        }
    }
    const float be0 = be[col];
    const float be1 = be[col + 16];

    const int wid = blockIdx.x * 4 + w;
    const int nw  = gridDim.x * 4;
    const int NT  = N_EDGES / 16;   // 100000 tiles, exact

    for (int tile = wid; tile < NT; tile += nw) {
        // edge metadata: lane serves edge row (l&15)
        const int4 p = perm[tile * 16 + col];

        const unsigned short* r0 = nfb + (size_t)p.x * F_NODE;
        const unsigned short* r1 = nfb + (size_t)p.y * F_NODE;
        const short8_t a0 = *reinterpret_cast<const short8_t*>(r0 + g * 8);        // k 0..31
        const short8_t a1 = *reinterpret_cast<const short8_t*>(r0 + 32 + g * 8);   // k 32..63
        const short8_t a2 = *reinterpret_cast<const short8_t*>(r1 + g * 8);        // k 64..95
        const short8_t a3 = *reinterpret_cast<const short8_t*>(r1 + 32 + g * 8);   // k 96..127

        const float* re = ef + (size_t)p.z * F_EDGE + g * 8;                       // k 128..159
        const float4 e0 = *reinterpret_cast<const float4*>(re);
        const float4 e1 = *reinterpret_cast<const float4*>(re + 4);
        short8_t a4;
        a4[0] = (short)f2bf(e0.x); a4[1] = (short)f2bf(e0.y);
        a4[2] = (short)f2bf(e0.z); a4[3] = (short)f2bf(e0.w);
        a4[4] = (short)f2bf(e1.x); a4[5] = (short)f2bf(e1.y);
        a4[6] = (short)f2bf(e1.z); a4[7] = (short)f2bf(e1.w);

        f32x4_t acc0 = {be0, be0, be0, be0};
        f32x4_t acc1 = {be1, be1, be1, be1};
        acc0 = __builtin_amdgcn_mfma_f32_16x16x32_bf16(a0, bfrag[0][0], acc0, 0, 0, 0);
        acc1 = __builtin_amdgcn_mfma_f32_16x16x32_bf16(a0, bfrag[0][1], acc1, 0, 0, 0);
        acc0 = __builtin_amdgcn_mfma_f32_16x16x32_bf16(a1, bfrag[1][0], acc0, 0, 0, 0);
        acc1 = __builtin_amdgcn_mfma_f32_16x16x32_bf16(a1, bfrag[1][1], acc1, 0, 0, 0);
        acc0 = __builtin_amdgcn_mfma_f32_16x16x32_bf16(a2, bfrag[2][0], acc0, 0, 0, 0);
        acc1 = __builtin_amdgcn_mfma_f32_16x16x32_bf16(a2, bfrag[2][1], acc1, 0, 0, 0);
        acc0 = __builtin_amdgcn_mfma_f32_16x16x32_bf16(a3, bfrag[3][0], acc0, 0, 0, 0);
        acc1 = __builtin_amdgcn_mfma_f32_16x16x32_bf16(a3, bfrag[3][1], acc1, 0, 0, 0);
        acc0 = __builtin_amdgcn_mfma_f32_16x16x32_bf16(a4, bfrag[4][0], acc0, 0, 0, 0);
        acc1 = __builtin_amdgcn_mfma_f32_16x16x32_bf16(a4, bfrag[4][1], acc1, 0, 0, 0);

        // ---- ReLU + bf16 pack, stage through per-wave LDS, coalesced store --
        unsigned short* cb = cbuf[w];
        #pragma unroll
        for (int r = 0; r < 4; ++r) {
            const int row = g * 4 + r;               // edge row within tile
            cb[row * MSG + col]      = f2bf(fmaxf(acc0[r], 0.0f));
            cb[row * MSG + 16 + col] = f2bf(fmaxf(acc1[r], 0.0f));
        }
        asm volatile("s_waitcnt lgkmcnt(0)" ::: "memory");   // same-wave RAW
        const uint4 vv = *reinterpret_cast<const uint4*>(cb + (l >> 2) * MSG + (l & 3) * 8);
        *reinterpret_cast<uint4*>(
            msgb + (size_t)(tile * 16 + (l >> 2)) * MSG + (l & 3) * 8) = vv;
        asm volatile("" ::: "memory");               // keep next iter's writes after read
    }
}

// ---------------------------------------------------------------------------
// Phase 5: wave-per-node segmented sum + node MLP  (proven round 4)
// ---------------------------------------------------------------------------
__global__ __launch_bounds__(256) void node_agg_mlp(
    const float* __restrict__ nf,
    const unsigned short* __restrict__ msgb,
    const int* __restrict__ base,
    const float* __restrict__ Wn,   // [96][64] row-major
    const float* __restrict__ bn,   // [64]
    float* __restrict__ out)        // [N_NODES][64]
{
    __shared__ float xbuf[4][96];
    const int lane = threadIdx.x & 63;
    const int w    = threadIdx.x >> 6;
    int n = blockIdx.x * 4 + w;                    // grid exact: 50000/4
    n = __builtin_amdgcn_readfirstlane(n);

    const int start = base[n];
    const int end   = base[n + 1];
    const int r = lane >> 2;        // 0..15
    const int q = lane & 3;         // 0..3

    float part[8];
    #pragma unroll
    for (int i = 0; i < 8; ++i) part[i] = 0.0f;

    for (int i = start + r; i < end; i += 16) {
        const uint4 v = reinterpret_cast<const uint4*>(msgb + (size_t)i * MSG)[q];
        part[0] += bf_lo(v.x); part[1] += bf_hi(v.x);
        part[2] += bf_lo(v.y); part[3] += bf_hi(v.y);
        part[4] += bf_lo(v.z); part[5] += bf_hi(v.z);
        part[6] += bf_lo(v.w); part[7] += bf_hi(v.w);
    }
    #pragma unroll
    for (int d = 4; d < 64; d <<= 1) {
        #pragma unroll
        for (int i = 0; i < 8; ++i) part[i] += __shfl_xor(part[i], d, 64);
    }

    float* xb = xbuf[w];
    xb[lane] = nf[(size_t)n * F_NODE + lane];
    if (r == 0) {
        #pragma unroll
        for (int i = 0; i < 8; ++i) xb[F_NODE + q * 8 + i] = part[i];
    }
    __syncthreads();

    float acc = bn[lane];
    #pragma unroll 8
    for (int k = 0; k < F_NODE + MSG; ++k)
        acc = fmaf(Wn[k * F_NODE + lane], xb[k], acc);

    out[(size_t)n * F_NODE + lane] = fmaxf(acc, 0.0f);
}

// ===========================================================================
// Fallback (round-1, proven): direct f32 atomic scatter + thread-per-node MLP
// ===========================================================================
__global__ __launch_bounds__(256) void edge_mlp_atomic(
    const float* __restrict__ nf, const int* __restrict__ eidx,
    const float* __restrict__ ef, const float* __restrict__ We,
    const float* __restrict__ be, float* __restrict__ msum)
{
    const int e = blockIdx.x * 256 + threadIdx.x;
    const int n0 = eidx[e];
    const int n1 = eidx[N_EDGES + e];
    const float4* x0 = reinterpret_cast<const float4*>(nf + (size_t)n0 * F_NODE);
    const float4* x1 = reinterpret_cast<const float4*>(nf + (size_t)n1 * F_NODE);
    const float4* xe = reinterpret_cast<const float4*>(ef + (size_t)e * F_EDGE);
    float acc[MSG];
    #pragma unroll
    for (int j = 0; j < MSG; ++j) acc[j] = be[j];
    #pragma unroll 2
    for (int c = 0; c < 16; ++c) {
        float4 v = x0[c];
        #pragma unroll
        for (int dk = 0; dk < 4; ++dk) {
            const float xv = (&v.x)[dk]; const int k = c * 4 + dk;
            #pragma unroll
            for (int j = 0; j < MSG; ++j) acc[j] = fmaf(We[k * MSG + j], xv, acc[j]);
        }
    }
    #pragma unroll 2
    for (int c = 0; c < 16; ++c) {
        float4 v = x1[c];
        #pragma unroll
        for (int dk = 0; dk < 4; ++dk) {
            const float xv = (&v.x)[dk]; const int k = 64 + c * 4 + dk;
            #pragma unroll
            for (int j = 0; j < MSG; ++j) acc[j] = fmaf(We[k * MSG + j], xv, acc[j]);
        }
    }
    #pragma unroll 2
    for (int c = 0; c < 8; ++c) {
        float4 v = xe[c];
        #pragma unroll
        for (int dk = 0; dk < 4; ++dk) {
            const float xv = (&v.x)[dk]; const int k = 128 + c * 4 + dk;
            #pragma unroll
            for (int j = 0; j < MSG; ++j) acc[j] = fmaf(We[k * MSG + j], xv, acc[j]);
        }
    }
    float* dst = msum + (size_t)n0 * MSG;
    #pragma unroll
    for (int j = 0; j < MSG; ++j) unsafeAtomicAdd(dst + j, fmaxf(acc[j], 0.0f));
}

__global__ __launch_bounds__(256) void node_mlp_thread(
    const float* __restrict__ nf, const float* __restrict__ msum,
    const float* __restrict__ Wn, const float* __restrict__ bn,
    float* __restrict__ out)
{
    const int n = blockIdx.x * 256 + threadIdx.x;
    if (n >= N_NODES) return;
    const float4* x0 = reinterpret_cast<const float4*>(nf + (size_t)n * F_NODE);
    const float4* x1 = reinterpret_cast<const float4*>(msum + (size_t)n * MSG);
    float acc[F_NODE];
    #pragma unroll
    for (int j = 0; j < F_NODE; ++j) acc[j] = bn[j];
    #pragma unroll 2
    for (int c = 0; c < 16; ++c) {
        float4 v = x0[c];
        #pragma unroll
        for (int dk = 0; dk < 4; ++dk) {
            const float xv = (&v.x)[dk]; const int k = c * 4 + dk;
            #pragma unroll
            for (int j = 0; j < F_NODE; ++j) acc[j] = fmaf(Wn[k * F_NODE + j], xv, acc[j]);
        }
    }
    #pragma unroll 2
    for (int c = 0; c < 8; ++c) {
        float4 v = x1[c];
        #pragma unroll
        for (int dk = 0; dk < 4; ++dk) {
            const float xv = (&v.x)[dk]; const int k = 64 + c * 4 + dk;
            #pragma unroll
            for (int j = 0; j < F_NODE; ++j) acc[j] = fmaf(Wn[k * F_NODE + j], xv, acc[j]);
        }
    }
    float4* o = reinterpret_cast<float4*>(out + (size_t)n * F_NODE);
    #pragma unroll
    for (int cc = 0; cc < 16; ++cc) {
        float4 v;
        v.x = fmaxf(acc[cc * 4 + 0], 0.0f);
        v.y = fmaxf(acc[cc * 4 + 1], 0.0f);
        v.z = fmaxf(acc[cc * 4 + 2], 0.0f);
        v.w = fmaxf(acc[cc * 4 + 3], 0.0f);
        o[cc] = v;
    }
}

// ===========================================================================
extern "C" void kernel_launch(void* const* d_in, const int* in_sizes, int n_in,
                              void* d_out, int out_size, void* d_ws, size_t ws_size,
                              hipStream_t stream) {
    const float* nf = (const float*)d_in[0];
    const int*   ei = (const int*)d_in[1];
    const float* ef = (const float*)d_in[2];
    const float* We = (const float*)d_in[3];
    const float* be = (const float*)d_in[4];
    const float* Wn = (const float*)d_in[5];
    const float* bn = (const float*)d_in[6];
    float* out = (float*)d_out;

    // ws: [msgb bf16 E*32][base N+1][cursor N][pad][nfb bf16 N*64][Webb bf16 5120][pad][perm int4 E]
    size_t off_base   = (size_t)N_EDGES * MSG * sizeof(unsigned short);   // 102.4 MB
    size_t off_cursor = off_base + (size_t)(N_NODES + 1) * sizeof(int);
    size_t off_nfb    = (off_cursor + (size_t)N_NODES * sizeof(int) + 15) & ~(size_t)15;
    size_t off_webb   = off_nfb + (size_t)NF_ELEMS * sizeof(unsigned short);
    size_t off_perm   = (off_webb + (size_t)WE_ELEMS * sizeof(unsigned short) + 15) & ~(size_t)15;
    const size_t need = off_perm + (size_t)N_EDGES * sizeof(int4);        // ~134.9 MB

    if (ws_size >= need) {
        char* ws = (char*)d_ws;
        unsigned short* msgb   = (unsigned short*)ws;
        int*            basep  = (int*)(ws + off_base);
        int*            cursor = (int*)(ws + off_cursor);
        unsigned short* nfb    = (unsigned short*)(ws + off_nfb);
        unsigned short* Webb   = (unsigned short*)(ws + off_webb);
        int4*           perm   = (int4*)(ws + off_perm);

        hipMemsetAsync(cursor, 0, (size_t)N_NODES * sizeof(int), stream);
        conv_all<<<(NF_ELEMS + WE_ELEMS) / 8 / 256, 256, 0, stream>>>(nf, We, nfb, Webb);
        hist_kernel<<<N_EDGES / 256, 256, 0, stream>>>(ei, cursor);
        scan_kernel<<<1, 1024, 0, stream>>>(cursor, basep);
        perm_kernel<<<N_EDGES / 256, 256, 0, stream>>>(ei, cursor, perm);
        edge_mlp_mfma<<<1024, 256, 0, stream>>>(nfb, perm, ef, Webb, be, msgb);
        node_agg_mlp<<<N_NODES / 4, 256, 0, stream>>>(nf, msgb, basep, Wn, bn, out);
    } else {
        float* msum = (float*)d_ws;
        hipMemsetAsync(msum, 0, (size_t)N_NODES * MSG * sizeof(float), stream);
        edge_mlp_atomic<<<N_EDGES / 256, 256, 0, stream>>>(nf, ei, ef, We, be, msum);
        node_mlp_thread<<<(N_NODES + 255) / 256, 256, 0, stream>>>(nf, msum, Wn, bn, out);
    }
}

// Round 6
// 386.980 us; speedup vs baseline: 7.0611x; 1.2424x over previous
//
#include <hip/hip_runtime.h>

#define N_NODES 50000
#define N_EDGES 1600000
#define F_NODE 64
#define F_EDGE 32
#define MSG 32
#define EDGE_IN 160                       // 2*F_NODE + F_EDGE
#define NF_ELEMS (N_NODES * F_NODE)       // 3,200,000
#define WE_ELEMS (EDGE_IN * MSG)          // 5,120

typedef __attribute__((ext_vector_type(8))) short short8_t;   // 8 bf16
typedef __attribute__((ext_vector_type(4))) float f32x4_t;    // MFMA acc

// ---------------------------------------------------------------------------
// bf16 helpers (RNE)
// ---------------------------------------------------------------------------
__device__ __forceinline__ unsigned short f2bf(float f) {
    unsigned u = __float_as_uint(f);
    return (unsigned short)((u + 0x7FFFu + ((u >> 16) & 1u)) >> 16);
}
__device__ __forceinline__ float bf_lo(unsigned w) { return __uint_as_float(w << 16); }
__device__ __forceinline__ float bf_hi(unsigned w) { return __uint_as_float(w & 0xFFFF0000u); }

// ---------------------------------------------------------------------------
// Phase 0: nf -> nfb (bf16), We -> Webb (bf16), zero cnt (folded memset)
// ---------------------------------------------------------------------------
__global__ __launch_bounds__(256) void conv_all(
    const float* __restrict__ nf, const float* __restrict__ We,
    unsigned short* __restrict__ nfb, unsigned short* __restrict__ Webb,
    int* __restrict__ cnt)
{
    const int tid = blockIdx.x * 256 + threadIdx.x;
    if (tid < N_NODES) cnt[tid] = 0;
    const int i = tid * 8;
    if (i < NF_ELEMS) {
        const float4 a = *reinterpret_cast<const float4*>(nf + i);
        const float4 b = *reinterpret_cast<const float4*>(nf + i + 4);
        uint4 o;
        o.x = (unsigned)f2bf(a.x) | ((unsigned)f2bf(a.y) << 16);
        o.y = (unsigned)f2bf(a.z) | ((unsigned)f2bf(a.w) << 16);
        o.z = (unsigned)f2bf(b.x) | ((unsigned)f2bf(b.y) << 16);
        o.w = (unsigned)f2bf(b.z) | ((unsigned)f2bf(b.w) << 16);
        *reinterpret_cast<uint4*>(nfb + i) = o;
    } else if (i < NF_ELEMS + WE_ELEMS) {
        const int j = i - NF_ELEMS;
        const float4 a = *reinterpret_cast<const float4*>(We + j);
        const float4 b = *reinterpret_cast<const float4*>(We + j + 4);
        uint4 o;
        o.x = (unsigned)f2bf(a.x) | ((unsigned)f2bf(a.y) << 16);
        o.y = (unsigned)f2bf(a.z) | ((unsigned)f2bf(a.w) << 16);
        o.z = (unsigned)f2bf(b.x) | ((unsigned)f2bf(b.y) << 16);
        o.w = (unsigned)f2bf(b.z) | ((unsigned)f2bf(b.w) << 16);
        *reinterpret_cast<uint4*>(Webb + j) = o;
    }
}

// ---------------------------------------------------------------------------
// Phase 1: histogram + per-edge rank in ONE atomic pass
// ---------------------------------------------------------------------------
__global__ __launch_bounds__(256) void hist_rank(
    const int* __restrict__ eidx, int* __restrict__ cnt, int* __restrict__ rank)
{
    const int e = blockIdx.x * 256 + threadIdx.x;   // grid exact
    rank[e] = atomicAdd(&cnt[eidx[e]], 1);
}

// ---------------------------------------------------------------------------
// Phase 2: single-block exclusive scan cnt -> base  (proven)
// ---------------------------------------------------------------------------
__global__ __launch_bounds__(1024) void scan_kernel(
    int* __restrict__ cnt_cursor, int* __restrict__ base)
{
    __shared__ int part[1024];
    const int t = threadIdx.x;
    const int CH = (N_NODES + 1023) / 1024;   // 49
    const int lo = t * CH;
    const int hi = min(lo + CH, N_NODES);
    int s = 0;
    for (int i = lo; i < hi; ++i) s += cnt_cursor[i];
    part[t] = s;
    __syncthreads();
    for (int off = 1; off < 1024; off <<= 1) {
        int u = (t >= off) ? part[t - off] : 0;
        __syncthreads();
        part[t] += u;
        __syncthreads();
    }
    int run = part[t] - s;
    for (int i = lo; i < hi; ++i) {
        int c = cnt_cursor[i];
        base[i] = run;
        cnt_cursor[i] = run;
        run += c;
    }
    if (t == 1023) base[N_NODES] = part[1023];
}

// ---------------------------------------------------------------------------
// Phase 3: edge MLP via MFMA, ORIGINAL edge order (all metadata coalesced,
// ef sequential). Output row written to CSR slot base[n0]+rank[e] (scattered
// 64B rows). MFMA fragments / LDS staging identical to proven r5 kernel.
//  A-frag (per lane): row = l&15 (edge in tile), k = (l>>4)*8 + j
//  B-frag (per lane): col = l&15, same k                (Webb wave-preloaded)
//  C/D   (verified m89): col = l&15, row = (l>>4)*4 + reg
// ---------------------------------------------------------------------------
__global__ __launch_bounds__(256) void edge_mlp_mfma(
    const unsigned short* __restrict__ nfb,
    const int* __restrict__ eidx,
    const int* __restrict__ rank,
    const int* __restrict__ base,
    const float* __restrict__ ef,
    const unsigned short* __restrict__ Webb,   // [160][32] bf16 row-major
    const float* __restrict__ be,              // [32] fp32
    unsigned short* __restrict__ msgb)         // [N_EDGES][32] bf16, CSR order
{
    __shared__ unsigned short cbuf[4][16 * MSG];   // per-wave private 1KB
    const int l   = threadIdx.x & 63;
    const int w   = threadIdx.x >> 6;
    const int col = l & 15;
    const int g   = l >> 4;

    // ---- B fragments: 5 K-steps x 2 N-tiles, loaded once per wave ----
    short8_t bfrag[5][2];
    #pragma unroll
    for (int s = 0; s < 5; ++s) {
        #pragma unroll
        for (int t = 0; t < 2; ++t) {
            short8_t v;
            #pragma unroll
            for (int j = 0; j < 8; ++j)
                v[j] = (short)Webb[s * 1024 + g * 256 + j * 32 + t * 16 + col];
            bfrag[s][t] = v;
        }
    }
    const float be0 = be[col];
    const float be1 = be[col + 16];

    const int wid = blockIdx.x * 4 + w;
    const int nw  = gridDim.x * 4;
    const int NT  = N_EDGES / 16;   // 100000 tiles, exact

    for (int tile = wid; tile < NT; tile += nw) {
        const int e  = tile * 16 + col;          // lane serves edge row (l&15)
        const int n0 = eidx[e];                  // coalesced
        const int n1 = eidx[N_EDGES + e];        // coalesced
        const int slot = base[n0] + rank[e];     // rank coalesced, base L2-hit

        const unsigned short* r0 = nfb + (size_t)n0 * F_NODE;
        const unsigned short* r1 = nfb + (size_t)n1 * F_NODE;
        const short8_t a0 = *reinterpret_cast<const short8_t*>(r0 + g * 8);        // k 0..31
        const short8_t a1 = *reinterpret_cast<const short8_t*>(r0 + 32 + g * 8);   // k 32..63
        const short8_t a2 = *reinterpret_cast<const short8_t*>(r1 + g * 8);        // k 64..95
        const short8_t a3 = *reinterpret_cast<const short8_t*>(r1 + 32 + g * 8);   // k 96..127

        const float* re = ef + (size_t)e * F_EDGE + g * 8;   // sequential rows
        const float4 e0 = *reinterpret_cast<const float4*>(re);
        const float4 e1 = *reinterpret_cast<const float4*>(re + 4);
        short8_t a4;
        a4[0] = (short)f2bf(e0.x); a4[1] = (short)f2bf(e0.y);
        a4[2] = (short)f2bf(e0.z); a4[3] = (short)f2bf(e0.w);
        a4[4] = (short)f2bf(e1.x); a4[5] = (short)f2bf(e1.y);
        a4[6] = (short)f2bf(e1.z); a4[7] = (short)f2bf(e1.w);

        f32x4_t acc0 = {be0, be0, be0, be0};
        f32x4_t acc1 = {be1, be1, be1, be1};
        acc0 = __builtin_amdgcn_mfma_f32_16x16x32_bf16(a0, bfrag[0][0], acc0, 0, 0, 0);
        acc1 = __builtin_amdgcn_mfma_f32_16x16x32_bf16(a0, bfrag[0][1], acc1, 0, 0, 0);
        acc0 = __builtin_amdgcn_mfma_f32_16x16x32_bf16(a1, bfrag[1][0], acc0, 0, 0, 0);
        acc1 = __builtin_amdgcn_mfma_f32_16x16x32_bf16(a1, bfrag[1][1], acc1, 0, 0, 0);
        acc0 = __builtin_amdgcn_mfma_f32_16x16x32_bf16(a2, bfrag[2][0], acc0, 0, 0, 0);
        acc1 = __builtin_amdgcn_mfma_f32_16x16x32_bf16(a2, bfrag[2][1], acc1, 0, 0, 0);
        acc0 = __builtin_amdgcn_mfma_f32_16x16x32_bf16(a3, bfrag[3][0], acc0, 0, 0, 0);
        acc1 = __builtin_amdgcn_mfma_f32_16x16x32_bf16(a3, bfrag[3][1], acc1, 0, 0, 0);
        acc0 = __builtin_amdgcn_mfma_f32_16x16x32_bf16(a4, bfrag[4][0], acc0, 0, 0, 0);
        acc1 = __builtin_amdgcn_mfma_f32_16x16x32_bf16(a4, bfrag[4][1], acc1, 0, 0, 0);

        // ---- ReLU + bf16 pack, stage via per-wave LDS, scatter 64B rows ----
        unsigned short* cb = cbuf[w];
        #pragma unroll
        for (int r = 0; r < 4; ++r) {
            const int row = g * 4 + r;               // edge row within tile
            cb[row * MSG + col]      = f2bf(fmaxf(acc0[r], 0.0f));
            cb[row * MSG + 16 + col] = f2bf(fmaxf(acc1[r], 0.0f));
        }
        asm volatile("s_waitcnt lgkmcnt(0)" ::: "memory");   // same-wave RAW
        const int dslot = __shfl(slot, l >> 2, 64);          // row (l>>2)'s slot
        const uint4 vv = *reinterpret_cast<const uint4*>(cb + (l >> 2) * MSG + (l & 3) * 8);
        *reinterpret_cast<uint4*>(
            msgb + (size_t)dslot * MSG + (l & 3) * 8) = vv;
        asm volatile("" ::: "memory");               // keep next iter's writes after read
    }
}

// ---------------------------------------------------------------------------
// Phase 4: wave-per-node segmented sum + node MLP  (proven r4/r5)
// ---------------------------------------------------------------------------
__global__ __launch_bounds__(256) void node_agg_mlp(
    const float* __restrict__ nf,
    const unsigned short* __restrict__ msgb,
    const int* __restrict__ base,
    const float* __restrict__ Wn,   // [96][64] row-major
    const float* __restrict__ bn,   // [64]
    float* __restrict__ out)        // [N_NODES][64]
{
    __shared__ float xbuf[4][96];
    const int lane = threadIdx.x & 63;
    const int w    = threadIdx.x >> 6;
    int n = blockIdx.x * 4 + w;                    // grid exact: 50000/4
    n = __builtin_amdgcn_readfirstlane(n);

    const int start = base[n];
    const int end   = base[n + 1];
    const int r = lane >> 2;        // 0..15
    const int q = lane & 3;         // 0..3

    float part[8];
    #pragma unroll
    for (int i = 0; i < 8; ++i) part[i] = 0.0f;

    for (int i = start + r; i < end; i += 16) {
        const uint4 v = reinterpret_cast<const uint4*>(msgb + (size_t)i * MSG)[q];
        part[0] += bf_lo(v.x); part[1] += bf_hi(v.x);
        part[2] += bf_lo(v.y); part[3] += bf_hi(v.y);
        part[4] += bf_lo(v.z); part[5] += bf_hi(v.z);
        part[6] += bf_lo(v.w); part[7] += bf_hi(v.w);
    }
    #pragma unroll
    for (int d = 4; d < 64; d <<= 1) {
        #pragma unroll
        for (int i = 0; i < 8; ++i) part[i] += __shfl_xor(part[i], d, 64);
    }

    float* xb = xbuf[w];
    xb[lane] = nf[(size_t)n * F_NODE + lane];
    if (r == 0) {
        #pragma unroll
        for (int i = 0; i < 8; ++i) xb[F_NODE + q * 8 + i] = part[i];
    }
    __syncthreads();

    float acc = bn[lane];
    #pragma unroll 8
    for (int k = 0; k < F_NODE + MSG; ++k)
        acc = fmaf(Wn[k * F_NODE + lane], xb[k], acc);

    out[(size_t)n * F_NODE + lane] = fmaxf(acc, 0.0f);
}

// ===========================================================================
// Fallback (round-1, proven): direct f32 atomic scatter + thread-per-node MLP
// ===========================================================================
__global__ __launch_bounds__(256) void edge_mlp_atomic(
    const float* __restrict__ nf, const int* __restrict__ eidx,
    const float* __restrict__ ef, const float* __restrict__ We,
    const float* __restrict__ be, float* __restrict__ msum)
{
    const int e = blockIdx.x * 256 + threadIdx.x;
    const int n0 = eidx[e];
    const int n1 = eidx[N_EDGES + e];
    const float4* x0 = reinterpret_cast<const float4*>(nf + (size_t)n0 * F_NODE);
    const float4* x1 = reinterpret_cast<const float4*>(nf + (size_t)n1 * F_NODE);
    const float4* xe = reinterpret_cast<const float4*>(ef + (size_t)e * F_EDGE);
    float acc[MSG];
    #pragma unroll
    for (int j = 0; j < MSG; ++j) acc[j] = be[j];
    #pragma unroll 2
    for (int c = 0; c < 16; ++c) {
        float4 v = x0[c];
        #pragma unroll
        for (int dk = 0; dk < 4; ++dk) {
            const float xv = (&v.x)[dk]; const int k = c * 4 + dk;
            #pragma unroll
            for (int j = 0; j < MSG; ++j) acc[j] = fmaf(We[k * MSG + j], xv, acc[j]);
        }
    }
    #pragma unroll 2
    for (int c = 0; c < 16; ++c) {
        float4 v = x1[c];
        #pragma unroll
        for (int dk = 0; dk < 4; ++dk) {
            const float xv = (&v.x)[dk]; const int k = 64 + c * 4 + dk;
            #pragma unroll
            for (int j = 0; j < MSG; ++j) acc[j] = fmaf(We[k * MSG + j], xv, acc[j]);
        }
    }
    #pragma unroll 2
    for (int c = 0; c < 8; ++c) {
        float4 v = xe[c];
        #pragma unroll
        for (int dk = 0; dk < 4; ++dk) {
            const float xv = (&v.x)[dk]; const int k = 128 + c * 4 + dk;
            #pragma unroll
            for (int j = 0; j < MSG; ++j) acc[j] = fmaf(We[k * MSG + j], xv, acc[j]);
        }
    }
    float* dst = msum + (size_t)n0 * MSG;
    #pragma unroll
    for (int j = 0; j < MSG; ++j) unsafeAtomicAdd(dst + j, fmaxf(acc[j], 0.0f));
}

__global__ __launch_bounds__(256) void node_mlp_thread(
    const float* __restrict__ nf, const float* __restrict__ msum,
    const float* __restrict__ Wn, const float* __restrict__ bn,
    float* __restrict__ out)
{
    const int n = blockIdx.x * 256 + threadIdx.x;
    if (n >= N_NODES) return;
    const float4* x0 = reinterpret_cast<const float4*>(nf + (size_t)n * F_NODE);
    const float4* x1 = reinterpret_cast<const float4*>(msum + (size_t)n * MSG);
    float acc[F_NODE];
    #pragma unroll
    for (int j = 0; j < F_NODE; ++j) acc[j] = bn[j];
    #pragma unroll 2
    for (int c = 0; c < 16; ++c) {
        float4 v = x0[c];
        #pragma unroll
        for (int dk = 0; dk < 4; ++dk) {
            const float xv = (&v.x)[dk]; const int k = c * 4 + dk;
            #pragma unroll
            for (int j = 0; j < F_NODE; ++j) acc[j] = fmaf(Wn[k * F_NODE + j], xv, acc[j]);
        }
    }
    #pragma unroll 2
    for (int c = 0; c < 8; ++c) {
        float4 v = x1[c];
        #pragma unroll
        for (int dk = 0; dk < 4; ++dk) {
            const float xv = (&v.x)[dk]; const int k = 64 + c * 4 + dk;
            #pragma unroll
            for (int j = 0; j < F_NODE; ++j) acc[j] = fmaf(Wn[k * F_NODE + j], xv, acc[j]);
        }
    }
    float4* o = reinterpret_cast<float4*>(out + (size_t)n * F_NODE);
    #pragma unroll
    for (int cc = 0; cc < 16; ++cc) {
        float4 v;
        v.x = fmaxf(acc[cc * 4 + 0], 0.0f);
        v.y = fmaxf(acc[cc * 4 + 1], 0.0f);
        v.z = fmaxf(acc[cc * 4 + 2], 0.0f);
        v.w = fmaxf(acc[cc * 4 + 3], 0.0f);
        o[cc] = v;
    }
}

// ===========================================================================
extern "C" void kernel_launch(void* const* d_in, const int* in_sizes, int n_in,
                              void* d_out, int out_size, void* d_ws, size_t ws_size,
                              hipStream_t stream) {
    const float* nf = (const float*)d_in[0];
    const int*   ei = (const int*)d_in[1];
    const float* ef = (const float*)d_in[2];
    const float* We = (const float*)d_in[3];
    const float* be = (const float*)d_in[4];
    const float* Wn = (const float*)d_in[5];
    const float* bn = (const float*)d_in[6];
    float* out = (float*)d_out;

    // ws: [msgb bf16 E*32][base N+1][cnt N][pad][nfb bf16][Webb bf16][pad][rank i32 E]
    size_t off_base = (size_t)N_EDGES * MSG * sizeof(unsigned short);     // 102.4 MB
    size_t off_cnt  = off_base + (size_t)(N_NODES + 1) * sizeof(int);
    size_t off_nfb  = (off_cnt + (size_t)N_NODES * sizeof(int) + 15) & ~(size_t)15;
    size_t off_webb = off_nfb + (size_t)NF_ELEMS * sizeof(unsigned short);
    size_t off_rank = (off_webb + (size_t)WE_ELEMS * sizeof(unsigned short) + 15) & ~(size_t)15;
    const size_t need = off_rank + (size_t)N_EDGES * sizeof(int);         // ~115.7 MB

    if (ws_size >= need) {
        char* ws = (char*)d_ws;
        unsigned short* msgb  = (unsigned short*)ws;
        int*            basep = (int*)(ws + off_base);
        int*            cnt   = (int*)(ws + off_cnt);
        unsigned short* nfb   = (unsigned short*)(ws + off_nfb);
        unsigned short* Webb  = (unsigned short*)(ws + off_webb);
        int*            rank  = (int*)(ws + off_rank);

        conv_all<<<(NF_ELEMS + WE_ELEMS) / 8 / 256, 256, 0, stream>>>(nf, We, nfb, Webb, cnt);
        hist_rank<<<N_EDGES / 256, 256, 0, stream>>>(ei, cnt, rank);
        scan_kernel<<<1, 1024, 0, stream>>>(cnt, basep);
        edge_mlp_mfma<<<1024, 256, 0, stream>>>(nfb, ei, rank, basep, ef, Webb, be, msgb);
        node_agg_mlp<<<N_NODES / 4, 256, 0, stream>>>(nf, msgb, basep, Wn, bn, out);
    } else {
        float* msum = (float*)d_ws;
        hipMemsetAsync(msum, 0, (size_t)N_NODES * MSG * sizeof(float), stream);
        edge_mlp_atomic<<<N_EDGES / 256, 256, 0, stream>>>(nf, ei, ef, We, be, msum);
        node_mlp_thread<<<(N_NODES + 255) / 256, 256, 0, stream>>>(nf, msum, Wn, bn, out);
    }
}